// Round 1
// baseline (320.064 us; speedup 1.0000x reference)
//
#include <hip/hip_runtime.h>

// ---------------------------------------------------------------------------
// SelfAttention (GN -> QKV 1x1 -> softmax(QK^T/16)V -> proj 1x1 + residual)
// B=8, C=256, GROUPS=32 (8 ch/group), H=W=64 -> T=4096. fp32 in/out,
// bf16 MFMA (16x16x32) internally.
//
// Pipeline (all gemm_bt shaped, K=256 contiguous on both operands):
//   conv_w     : wq,wk,wv,wp fp32 -> bf16 in ws
//   gn_stats   : per-(b,g) mean/rstd
//   gn_apply   : normalize + transpose -> h_t (B,T,C) bf16
//   gemm Q,K   : (B*T,256)x(256,256)^T -> Qs (scaled 1/16), Ks  (B,T,C) bf16
//   gemm V     : per batch (256,256)x(T,256)^T -> Vt (B,C,T) bf16
//   attn       : streaming softmax (no max subtraction; scores ~N(0,1)),
//                O accumulated unnormalized, divide by rowsum at end
//   gemm proj  : per batch (256,256)x(T,256)^T + bias + x -> d_out (B,C,T) f32
// ---------------------------------------------------------------------------

typedef unsigned short u16;
typedef __attribute__((ext_vector_type(8))) short short8;   // 8 bf16 = 4 VGPR
typedef __attribute__((ext_vector_type(4))) float f32x4;    // MFMA C/D

#define MFMA16(a, b, c) __builtin_amdgcn_mfma_f32_16x16x32_bf16((a), (b), (c), 0, 0, 0)

// async global->LDS, 16B per lane, dst = uniform base + lane*16
#define GLL16(g, l)                                                            \
  __builtin_amdgcn_global_load_lds(                                            \
      (const __attribute__((address_space(1))) void*)(g),                      \
      (__attribute__((address_space(3))) void*)(l), 16, 0, 0)

__device__ __forceinline__ u16 f2bf(float f) {  // RNE fp32 -> bf16 bits
  union { float f; unsigned u; } v; v.f = f;
  unsigned u = v.u;
  return (u16)((u + 0x7FFFu + ((u >> 16) & 1u)) >> 16);
}

// ---------------------------------------------------------------------------
// 0) weights fp32 -> bf16 (4 matrices of 256x256, contiguous in ws)
__global__ __launch_bounds__(256) void conv_w(const float* __restrict__ s0,
                                              const float* __restrict__ s1,
                                              const float* __restrict__ s2,
                                              const float* __restrict__ s3,
                                              u16* __restrict__ dst) {
  const int m = blockIdx.y;
  const float* s = (m == 0) ? s0 : (m == 1) ? s1 : (m == 2) ? s2 : s3;
  const int i = (blockIdx.x * 256 + threadIdx.x) * 4;
  float4 v = *(const float4*)(s + i);
  u16* d = dst + m * 65536 + i;
  d[0] = f2bf(v.x); d[1] = f2bf(v.y); d[2] = f2bf(v.z); d[3] = f2bf(v.w);
}

// ---------------------------------------------------------------------------
// 1) GroupNorm stats: one block per (b,g); the group's data is one contiguous
//    32768-float chunk of x. fp32 sum/sumsq, E[x^2]-E[x]^2.
__global__ __launch_bounds__(256) void gn_stats(const float* __restrict__ x,
                                                float2* __restrict__ stats) {
  const int bg = blockIdx.x;
  const float* p = x + (long)bg * 32768;
  const int tid = threadIdx.x;
  float s = 0.f, ss = 0.f;
  #pragma unroll 8
  for (int i = 0; i < 32; ++i) {
    float4 v = *(const float4*)(p + tid * 4 + i * 1024);
    s  += v.x + v.y + v.z + v.w;
    ss += v.x * v.x + v.y * v.y + v.z * v.z + v.w * v.w;
  }
  for (int off = 32; off; off >>= 1) {
    s  += __shfl_down(s, off);
    ss += __shfl_down(ss, off);
  }
  __shared__ float2 red[4];
  if ((tid & 63) == 0) red[tid >> 6] = make_float2(s, ss);
  __syncthreads();
  if (tid == 0) {
    float S  = red[0].x + red[1].x + red[2].x + red[3].x;
    float SS = red[0].y + red[1].y + red[2].y + red[3].y;
    float mean = S * (1.f / 32768.f);
    float var  = SS * (1.f / 32768.f) - mean * mean;
    stats[bg] = make_float2(mean, rsqrtf(var + 1e-5f));
  }
}

// ---------------------------------------------------------------------------
// 2) normalize + transpose: x (B,C,T) f32 -> h_t (B,T,C) bf16.
//    64x64 tiles through LDS; both global sides coalesced.
__global__ __launch_bounds__(256) void gn_apply(const float* __restrict__ x,
                                                const float2* __restrict__ stats,
                                                const float* __restrict__ gamma,
                                                const float* __restrict__ beta,
                                                u16* __restrict__ h_t) {
  __shared__ float tile[64][65];
  const int tid = threadIdx.x;
  const int b = blockIdx.z, c0 = blockIdx.y * 64, t0 = blockIdx.x * 64;
  {
    const int ci = tid >> 2, tj0 = (tid & 3) * 16;
    const int c = c0 + ci;
    float2 st = stats[b * 32 + (c >> 3)];
    float gm = gamma[c] * st.y;          // (x-mean)*rstd*gamma+beta = x*gm+bt
    float bt = beta[c] - st.x * gm;
    const float* xp = x + ((long)(b * 256 + c) * 4096 + t0 + tj0);
    #pragma unroll
    for (int i = 0; i < 4; ++i) {
      float4 v = *(const float4*)(xp + i * 4);
      tile[ci][tj0 + i * 4 + 0] = v.x * gm + bt;
      tile[ci][tj0 + i * 4 + 1] = v.y * gm + bt;
      tile[ci][tj0 + i * 4 + 2] = v.z * gm + bt;
      tile[ci][tj0 + i * 4 + 3] = v.w * gm + bt;
    }
  }
  __syncthreads();
  {
    const int tj = tid >> 2, ci0 = (tid & 3) * 16;
    u16* hp = h_t + ((long)(b * 4096 + t0 + tj) * 256 + c0 + ci0);
    short8 v0, v1;
    #pragma unroll
    for (int i = 0; i < 8; ++i) v0[i] = (short)f2bf(tile[ci0 + i][tj]);
    #pragma unroll
    for (int i = 0; i < 8; ++i) v1[i] = (short)f2bf(tile[ci0 + 8 + i][tj]);
    *(short8*)hp = v0;
    *(short8*)(hp + 8) = v1;
  }
}

// ---------------------------------------------------------------------------
// gemm_bt: C[m][n] = sum_k A[m][k]*B[n][k] + bias, K=256. Both operands
// K-contiguous bf16. 128x128 tile, BK=32, 4 waves (64x64 quadrant each),
// global_load_lds staging with 2-bit XOR granule swizzle (conflict-free b128
// fragment reads, coalescing preserved within 64B).
//   ROW_BIAS=false: bias over n (Q/K), bf16 out, (acc+bias)*scale
//   ROW_BIAS=true : bias over m (V/proj)
//   RESID=true    : fp32 out = acc + bias + resid (proj)
template <bool ROW_BIAS, bool RESID>
__global__ __launch_bounds__(256, 2) void gemm_bt(
    const u16* __restrict__ A, long strideAz, const u16* __restrict__ B,
    long strideBz, const float* __restrict__ bias, float scale,
    u16* __restrict__ outb, float* __restrict__ outf,
    const float* __restrict__ resid, long strideOz, int N) {
  __shared__ u16 a_lds[128 * 32];
  __shared__ u16 b_lds[128 * 32];
  const int tid = threadIdx.x, w = tid >> 6, l = tid & 63;
  const int l15 = l & 15, l4 = l >> 4;
  const int bz = blockIdx.z;
  A += bz * strideAz;
  B += bz * strideBz;
  const long obase = (long)bz * strideOz;
  const int m0 = blockIdx.y * 128, n0 = blockIdx.x * 128;
  const int wm = (w >> 1) * 64, wn = (w & 1) * 64;

  f32x4 acc[4][4];
  #pragma unroll
  for (int i = 0; i < 4; ++i)
    #pragma unroll
    for (int j = 0; j < 4; ++j) acc[i][j] = (f32x4)0.f;

  for (int kt = 0; kt < 8; ++kt) {
    const int k0 = kt * 32;
    __syncthreads();
    #pragma unroll
    for (int j = 0; j < 2; ++j) {
      const int r0 = (w * 2 + j) * 16;
      const int row = r0 + (l >> 2);
      const int sg = (l & 3) ^ (row & 3);          // swizzled data granule
      GLL16(A + (long)(m0 + row) * 256 + k0 + sg * 8, a_lds + r0 * 32);
      GLL16(B + (long)(n0 + row) * 256 + k0 + sg * 8, b_lds + r0 * 32);
    }
    __syncthreads();
    short8 af[4], bf[4];
    #pragma unroll
    for (int t = 0; t < 4; ++t) {
      const int ra = wm + t * 16 + l15;
      af[t] = *(const short8*)(a_lds + ra * 32 + ((l4 ^ (ra & 3)) * 8));
      const int rb = wn + t * 16 + l15;
      bf[t] = *(const short8*)(b_lds + rb * 32 + ((l4 ^ (rb & 3)) * 8));
    }
    #pragma unroll
    for (int mt = 0; mt < 4; ++mt)
      #pragma unroll
      for (int nt = 0; nt < 4; ++nt) acc[mt][nt] = MFMA16(af[mt], bf[nt], acc[mt][nt]);
  }

  // epilogue. C/D layout: col = l15, row = l4*4 + reg  [guide §3, m89-verified]
  if (!ROW_BIAS) {
    float bv[4];
    #pragma unroll
    for (int nt = 0; nt < 4; ++nt) bv[nt] = bias[n0 + wn + nt * 16 + l15];
    #pragma unroll
    for (int mt = 0; mt < 4; ++mt)
      #pragma unroll
      for (int nt = 0; nt < 4; ++nt)
        #pragma unroll
        for (int r = 0; r < 4; ++r) {
          const int row = m0 + wm + mt * 16 + l4 * 4 + r;
          const int col = n0 + wn + nt * 16 + l15;
          outb[obase + (long)row * N + col] = f2bf((acc[mt][nt][r] + bv[nt]) * scale);
        }
  } else {
    float bm[4][4];
    #pragma unroll
    for (int mt = 0; mt < 4; ++mt)
      #pragma unroll
      for (int r = 0; r < 4; ++r) bm[mt][r] = bias[m0 + wm + mt * 16 + l4 * 4 + r];
    #pragma unroll
    for (int mt = 0; mt < 4; ++mt)
      #pragma unroll
      for (int nt = 0; nt < 4; ++nt)
        #pragma unroll
        for (int r = 0; r < 4; ++r) {
          const int row = m0 + wm + mt * 16 + l4 * 4 + r;
          const int col = n0 + wn + nt * 16 + l15;
          const long idx = obase + (long)row * N + col;
          float v = acc[mt][nt][r] + bm[mt][r];
          if (RESID) outf[idx] = v + resid[idx];
          else       outb[idx] = f2bf(v);
        }
  }
}

// ---------------------------------------------------------------------------
// attention: per block one (batch, 64-row Q tile). BN=64 K/V tiles streamed.
// No-max online softmax (scores ~N(0,1), |s|max ~ 6 -> exp safe in fp32).
// Wave layout: S quadrant rows 32*(w>>1), cols 32*(w&1); O half-rows
// 32*(w>>1), cols 128*(w&1). P transits LDS (C-layout -> A-layout).
// p_lds + l_buf alias k_lds (barriers order the phases). LDS total = 64 KiB.
__global__ __launch_bounds__(256, 2) void attn_kernel(
    const u16* __restrict__ Qs, const u16* __restrict__ Ks,
    const u16* __restrict__ Vt, u16* __restrict__ Z) {
  __shared__ u16 k_lds[16384];  // 64 rows x 256 (swizzled granules), 32 KiB
  __shared__ u16 v_lds[16384];  // 256 rows x 64 (swizzled granules), 32 KiB
  u16* p_lds = k_lds;           // 64 x 72 bf16 (pad 8 -> conflict-free b128)
  float* l_buf = (float*)&k_lds[8192];  // byte 16384: 2 x 64 rowsums

  const int tid = threadIdx.x, w = tid >> 6, l = tid & 63;
  const int l15 = l & 15, l4 = l >> 4;
  const int bid = blockIdx.x;
  const int batch = bid & 7;   // bid%8: one batch per XCD if XCD = bid%8
  const int qt = bid >> 3;
  const int wrow0 = (w >> 1) * 32, wcolS = (w & 1) * 32, wcolO = (w & 1) * 128;
  const long qrow_base = (long)batch * 4096 + qt * 64;

  // Q fragments in registers: rows wrow0..wrow0+31, all 256 k. 64 VGPR.
  short8 qf[2][8];
  {
    const u16* qp = Qs + (qrow_base + wrow0) * 256;
    #pragma unroll
    for (int mt = 0; mt < 2; ++mt)
      #pragma unroll
      for (int ks = 0; ks < 8; ++ks)
        qf[mt][ks] = *(const short8*)(qp + (mt * 16 + l15) * 256 + ks * 32 + l4 * 8);
  }

  f32x4 o_acc[2][8];
  #pragma unroll
  for (int mt = 0; mt < 2; ++mt)
    #pragma unroll
    for (int nt = 0; nt < 8; ++nt) o_acc[mt][nt] = (f32x4)0.f;
  float rs[2][4] = {{0.f, 0.f, 0.f, 0.f}, {0.f, 0.f, 0.f, 0.f}};

  const u16* kbase = Ks + (long)batch * 4096 * 256;
  const u16* vbase = Vt + (long)batch * 256 * 4096;

  for (int st = 0; st < 64; ++st) {
    const int sn0 = st * 64;
    __syncthreads();  // prior PV reads of p_lds/v_lds done
    // stage K tile (rows = s-positions), 3-bit XOR swizzle within 512B rows
    #pragma unroll
    for (int j = 0; j < 8; ++j) {
      const int r0 = (j * 4 + w) * 2;
      const int row = r0 + (l >> 5);
      const int sg = (l & 31) ^ (row & 7);
      GLL16(kbase + (long)(sn0 + row) * 256 + sg * 8, k_lds + r0 * 256);
    }
    // stage V tile (rows = channels, 128B per row), swizzle within 128B
    #pragma unroll
    for (int j = 0; j < 8; ++j) {
      const int c0 = (j * 4 + w) * 8;
      const int c = c0 + (l >> 3);
      const int sg = (l & 7) ^ (c & 7);
      GLL16(vbase + (long)c * 4096 + sn0 + sg * 8, v_lds + c0 * 64);
    }
    __syncthreads();

    // S = Q K^T (quadrant 32x32), Q prescaled by 1/16
    f32x4 sacc[2][2];
    #pragma unroll
    for (int i = 0; i < 2; ++i)
      #pragma unroll
      for (int j = 0; j < 2; ++j) sacc[i][j] = (f32x4)0.f;
    #pragma unroll
    for (int ks = 0; ks < 8; ++ks) {
      short8 kf[2];
      #pragma unroll
      for (int nt = 0; nt < 2; ++nt) {
        const int row = wcolS + nt * 16 + l15;
        const int gk = (ks * 4 + l4) ^ (row & 7);
        kf[nt] = *(const short8*)(k_lds + row * 256 + gk * 8);
      }
      #pragma unroll
      for (int mt = 0; mt < 2; ++mt)
        #pragma unroll
        for (int nt = 0; nt < 2; ++nt) sacc[mt][nt] = MFMA16(qf[mt][ks], kf[nt], sacc[mt][nt]);
    }
    __syncthreads();  // all waves done reading k_lds before P overwrites it

    // P = exp(S); accumulate rowsums; write P to LDS (C-layout scatter)
    #pragma unroll
    for (int mt = 0; mt < 2; ++mt)
      #pragma unroll
      for (int nt = 0; nt < 2; ++nt)
        #pragma unroll
        for (int r = 0; r < 4; ++r) {
          float p = __expf(sacc[mt][nt][r]);
          rs[mt][r] += p;
          const int prow = wrow0 + mt * 16 + l4 * 4 + r;
          const int pcol = wcolS + nt * 16 + l15;
          p_lds[prow * 72 + pcol] = f2bf(p);
        }
    __syncthreads();

    // O += P V  (A-frags from p_lds, B-frags from v_lds)
    #pragma unroll
    for (int ks2 = 0; ks2 < 2; ++ks2) {
      short8 pa[2];
      #pragma unroll
      for (int mt = 0; mt < 2; ++mt)
        pa[mt] = *(const short8*)(p_lds + (wrow0 + mt * 16 + l15) * 72 + ks2 * 32 + l4 * 8);
      #pragma unroll
      for (int nt = 0; nt < 8; ++nt) {
        const int c = wcolO + nt * 16 + l15;
        const int gv = (ks2 * 4 + l4) ^ (c & 7);
        short8 vb = *(const short8*)(v_lds + c * 64 + gv * 8);
        #pragma unroll
        for (int mt = 0; mt < 2; ++mt) o_acc[mt][nt] = MFMA16(pa[mt], vb, o_acc[mt][nt]);
      }
    }
  }

  // rowsum: reduce across the 16 lanes of each quad-group
  #pragma unroll
  for (int mt = 0; mt < 2; ++mt)
    #pragma unroll
    for (int r = 0; r < 4; ++r) {
      float v = rs[mt][r];
      v += __shfl_xor(v, 1); v += __shfl_xor(v, 2);
      v += __shfl_xor(v, 4); v += __shfl_xor(v, 8);
      rs[mt][r] = v;
    }
  if (l15 == 0) {
    #pragma unroll
    for (int mt = 0; mt < 2; ++mt)
      #pragma unroll
      for (int r = 0; r < 4; ++r)
        l_buf[(w & 1) * 64 + wrow0 + mt * 16 + l4 * 4 + r] = rs[mt][r];
  }
  __syncthreads();

  // normalize + store Z (B,T,C) bf16
  #pragma unroll
  for (int mt = 0; mt < 2; ++mt) {
    float inv[4];
    #pragma unroll
    for (int r = 0; r < 4; ++r) {
      const int row = wrow0 + mt * 16 + l4 * 4 + r;
      inv[r] = 1.f / (l_buf[row] + l_buf[64 + row]);
    }
    #pragma unroll
    for (int nt = 0; nt < 8; ++nt) {
      const int col = wcolO + nt * 16 + l15;
      #pragma unroll
      for (int r = 0; r < 4; ++r) {
        const long row = qrow_base + wrow0 + mt * 16 + l4 * 4 + r;
        Z[row * 256 + col] = f2bf(o_acc[mt][nt][r] * inv[r]);
      }
    }
  }
}

// ---------------------------------------------------------------------------
extern "C" void kernel_launch(void* const* d_in, const int* in_sizes, int n_in,
                              void* d_out, int out_size, void* d_ws, size_t ws_size,
                              hipStream_t stream) {
  (void)in_sizes; (void)n_in; (void)out_size; (void)ws_size;
  const float* x     = (const float*)d_in[0];
  const float* gamma = (const float*)d_in[1];
  const float* beta  = (const float*)d_in[2];
  const float* wq    = (const float*)d_in[3];
  const float* bq    = (const float*)d_in[4];
  const float* wk    = (const float*)d_in[5];
  const float* bk    = (const float*)d_in[6];
  const float* wv    = (const float*)d_in[7];
  const float* bv    = (const float*)d_in[8];
  const float* wp    = (const float*)d_in[9];
  const float* bp    = (const float*)d_in[10];
  float* out = (float*)d_out;

  char* ws = (char*)d_ws;
  // ws layout (bytes): weights_bf16 | stats | h_t | Qs | Ks | Vt | Z  (~80.5 MiB)
  u16*    wb    = (u16*)(ws);                  // 4 x 65536 bf16
  float2* stats = (float2*)(ws + 524288);      // 256 x float2
  u16*    h_t   = (u16*)(ws + 526336);         // (B,T,C) bf16
  u16*    Qs    = (u16*)(ws + 17303552);       // (B,T,C) bf16, prescaled /16
  u16*    Ks    = (u16*)(ws + 34080768);       // (B,T,C) bf16
  u16*    Vt    = (u16*)(ws + 50857984);       // (B,C,T) bf16
  u16*    Zb    = (u16*)(ws + 67635200);       // (B,T,C) bf16

  conv_w<<<dim3(64, 4), dim3(256), 0, stream>>>(wq, wk, wv, wp, wb);
  gn_stats<<<dim3(256), dim3(256), 0, stream>>>(x, stats);
  gn_apply<<<dim3(64, 4, 8), dim3(256), 0, stream>>>(x, stats, gamma, beta, h_t);

  const long sB = 4096L * 256L, sO = 256L * 4096L;
  // Q: (32768x256)x(256x256)^T, scale 1/16 folded in
  gemm_bt<false, false><<<dim3(2, 256, 1), dim3(256), 0, stream>>>(
      h_t, 0L, wb, 0L, bq, 0.0625f, Qs, nullptr, nullptr, 0L, 256);
  // K
  gemm_bt<false, false><<<dim3(2, 256, 1), dim3(256), 0, stream>>>(
      h_t, 0L, wb + 65536, 0L, bk, 1.0f, Ks, nullptr, nullptr, 0L, 256);
  // V^T per batch: (256x256)x(4096x256)^T -> (B,C,T)
  gemm_bt<true, false><<<dim3(32, 2, 8), dim3(256), 0, stream>>>(
      wb + 2 * 65536, 0L, h_t, sB, bv, 1.0f, Vt, nullptr, nullptr, sO, 4096);

  attn_kernel<<<dim3(512), dim3(256), 0, stream>>>(Qs, Ks, Vt, Zb);

  // proj per batch + bias + residual -> fp32 out (B,C,T)
  gemm_bt<true, true><<<dim3(32, 2, 8), dim3(256), 0, stream>>>(
      wb + 3 * 65536, 0L, Zb, sB, bp, 1.0f, nullptr, out, x, sO, 4096);
}